// Round 1
// baseline (826.368 us; speedup 1.0000x reference)
//
#include <hip/hip_runtime.h>

typedef _Float16 f16;
typedef _Float16 f16x4 __attribute__((ext_vector_type(4)));
typedef _Float16 f16x8 __attribute__((ext_vector_type(8)));
typedef float f32x4 __attribute__((ext_vector_type(4)));

#define MFMA_F16(A, B, C) __builtin_amdgcn_mfma_f32_16x16x32_f16(A, B, C, 0, 0, 0)

// x: [32,64,64,384] fp32 -> windows of 8x8 -> 2048 windows x 64 tokens
// heads=12, dim_head=32, INNER=384, qkv cols = 1152
static constexpr int ROWS = 32 * 64 * 64;  // 131072 token rows
static constexpr float SCALE = 0.17677669529663687f;  // 32^-0.5

// workspace layout (bytes)
static constexpr size_t WQKVT_OFF = 0;                              // f16 [1152][384] (B^T)
static constexpr size_t WOUTT_OFF = (size_t)1152 * 384 * 2;         // f16 [384][384]  (B^T)
static constexpr size_t QKV_OFF   = WOUTT_OFF + (size_t)384 * 384 * 2;  // f16 [131072][1152]
static constexpr size_t WS_NEEDED = QKV_OFF + (size_t)ROWS * 1152 * 2;  // ~303 MB

// ---------------- weight prep: transpose + fp32->fp16 ----------------
__global__ __launch_bounds__(256) void k_prep(const float* __restrict__ wqkv,
                                              const float* __restrict__ wout,
                                              f16* __restrict__ wqkvT,
                                              f16* __restrict__ woutT) {
  int idx = blockIdx.x * 256 + threadIdx.x;
  if (idx < 1152 * 384) {
    int c = idx / 384, k = idx - c * 384;
    wqkvT[idx] = (f16)wqkv[k * 1152 + c];
  } else {
    int i = idx - 1152 * 384;
    if (i < 384 * 384) {
      int c = i / 384, k = i - c * 384;
      woutT[i] = (f16)wout[k * 384 + c];
    }
  }
}

// ---------------- QKV GEMM: [131072,384](fp32) @ [384,1152] -> fp16 ----------------
// 128x128 tile, BK=64, 4 waves in 2x2, 16x16x32 fp16 MFMA.
// v2: B fragments read DIRECTLY from global (w_qkvT is 884KB, L2-resident) -> no B LDS
//     traffic at all. A double-buffered in padded LDS; A loads + B frags for step k+1
//     issued before the MFMA phase of step k (one barrier per K-step).
__global__ __launch_bounds__(256) void k_qkv(const float* __restrict__ X,
                                             const f16* __restrict__ Wt,
                                             f16* __restrict__ qkv) {
  __shared__ f16 As[2][128 * 72];  // 2 x 18,432 B = 36,864 B (padded: 72 halves/row)

  const int tid = threadIdx.x;
  // XCD swizzle: id%8 = XCD (dispatch round-robin). Per XCD, 9 consecutive
  // blocks share one m-tile so the A-tile is fetched into that XCD's L2 once.
  const int id = blockIdx.x;          // 0..9215
  const int s = id & 7, t = id >> 3;  // t in [0,1152)
  const int n0 = (t % 9) * 128;
  const int m0 = (s * 128 + t / 9) * 128;

  const int lane = tid & 63, wave = tid >> 6;
  const int lane15 = lane & 15, quad = lane >> 4;
  const int wm = (wave >> 1) * 64, wn = (wave & 1) * 64;

  const int arow = tid >> 4;        // + l*16 -> staged A row
  const int ac4 = (tid & 15) * 4;   // staged A col group (4 floats)

  // per-(j) B fragment base pointers (exactly the address pattern the old LDS
  // staging reproduced): frag(ks,kk) = bp[j] + ks + kk*32
  const f16* bp[4];
#pragma unroll
  for (int j = 0; j < 4; ++j)
    bp[j] = Wt + (size_t)(n0 + wn + j * 16 + lane15) * 384 + quad * 8;

  float4 xv[8];
  f16x8 bf[2][2][4];  // [buf][kk][j] -- statically indexed after full unroll

  // ---- prologue: fetch ks=0 (A regs + B frags), stage A into As[0] ----
#pragma unroll
  for (int l = 0; l < 8; ++l)
    xv[l] = *(const float4*)&X[(size_t)(m0 + l * 16 + arow) * 384 + ac4];
#pragma unroll
  for (int kk = 0; kk < 2; ++kk)
#pragma unroll
    for (int j = 0; j < 4; ++j)
      bf[0][kk][j] = *(const f16x8*)(bp[j] + kk * 32);
#pragma unroll
  for (int l = 0; l < 8; ++l) {
    f16x4 hv;
    hv[0] = (f16)xv[l].x; hv[1] = (f16)xv[l].y; hv[2] = (f16)xv[l].z; hv[3] = (f16)xv[l].w;
    *(f16x4*)&As[0][(l * 16 + arow) * 72 + ac4] = hv;
  }
  __syncthreads();

  f32x4 acc[4][4] = {};
#pragma unroll
  for (int ksi = 0; ksi < 6; ++ksi) {
    const int cur = ksi & 1, nxt = cur ^ 1;
    const int ks = ksi * 64;

    // ---- prefetch step ks+64 (issued BEFORE compute so latency hides under MFMA) ----
    if (ksi < 5) {
#pragma unroll
      for (int l = 0; l < 8; ++l)
        xv[l] = *(const float4*)&X[(size_t)(m0 + l * 16 + arow) * 384 + ks + 64 + ac4];
#pragma unroll
      for (int kk = 0; kk < 2; ++kk)
#pragma unroll
        for (int j = 0; j < 4; ++j)
          bf[nxt][kk][j] = *(const f16x8*)(bp[j] + ks + 64 + kk * 32);
    }

    // ---- compute on As[cur] / bf[cur] ----
#pragma unroll
    for (int kk = 0; kk < 2; ++kk) {
      f16x8 af[4];
#pragma unroll
      for (int i = 0; i < 4; ++i)
        af[i] = *(const f16x8*)&As[cur][(wm + i * 16 + lane15) * 72 + kk * 32 + quad * 8];
#pragma unroll
      for (int i = 0; i < 4; ++i)
#pragma unroll
        for (int j = 0; j < 4; ++j)
          acc[i][j] = MFMA_F16(af[i], bf[cur][kk][j], acc[i][j]);
    }

    // ---- write-late: convert prefetched A and stage into the other buffer ----
    if (ksi < 5) {
#pragma unroll
      for (int l = 0; l < 8; ++l) {
        f16x4 hv;
        hv[0] = (f16)xv[l].x; hv[1] = (f16)xv[l].y; hv[2] = (f16)xv[l].z; hv[3] = (f16)xv[l].w;
        *(f16x4*)&As[nxt][(l * 16 + arow) * 72 + ac4] = hv;
      }
    }
    __syncthreads();  // one barrier per K-step (read cur done + write nxt visible)
  }

  // epilogue: fp32 acc -> fp16, bounce through LDS for coalesced 16B stores
  f16* Cs = (f16*)As;  // needs 128*136*2 = 34,816 B <= 36,864 B
#pragma unroll
  for (int i = 0; i < 4; ++i)
#pragma unroll
    for (int j = 0; j < 4; ++j)
#pragma unroll
      for (int v = 0; v < 4; ++v)
        Cs[(wm + i * 16 + quad * 4 + v) * 136 + wn + j * 16 + lane15] = (f16)acc[i][j][v];
  __syncthreads();
#pragma unroll
  for (int l = 0; l < 8; ++l) {
    int idx = l * 256 + tid;
    int row = idx >> 4, c8 = (idx & 15) * 8;
    *(f16x8*)&qkv[(size_t)(m0 + row) * 1152 + n0 + c8] = *(const f16x8*)&Cs[row * 136 + c8];
  }
}

// ---------------- attention per window + fused out-projection ----------------
// block = 256 thr (4 waves), one block per window. wave w owns score rows w*16..w*16+15.
__global__ __launch_bounds__(256) void k_attn(const f16* __restrict__ qkv,
                                              const f16* __restrict__ woutT,
                                              const float* __restrict__ b_out,
                                              float* __restrict__ out) {
  __shared__ f16 vt[32 * 72];     // v^T for current head: [dim][64 tok + 8 pad]
  __shared__ f16 Pw[4][16 * 72];  // per-wave P tile [16][64+8]
  __shared__ f16 ao[64 * 392];    // attention output [64][384+8]
  // total LDS = 64,000 B -> 2 blocks/CU

  const int tid = threadIdx.x;
  const int lane = tid & 63, wave = tid >> 6;
  const int lane15 = lane & 15, quad = lane >> 4;

  const int blk = blockIdx.x;  // 0..2047
  const int b = blk >> 6, rem = blk & 63, wh = rem >> 3, ww = rem & 7;
  const int base = b * 4096 + wh * 512 + ww * 8;  // natural row of token (0,0)

  // per-lane source rows (token t -> natural row base + (t>>3)*64 + (t&7))
  const int tq = wave * 16 + lane15;
  const size_t rowq = (size_t)(base + (tq >> 3) * 64 + (tq & 7)) * 1152;
  size_t rowk[4];
#pragma unroll
  for (int tj = 0; tj < 4; ++tj) {
    int tk = tj * 16 + lane15;
    rowk[tj] = (size_t)(base + (tk >> 3) * 64 + (tk & 7)) * 1152;
  }
  const int vt_t = tid >> 2, vt_d8 = (tid & 3) * 8;
  const size_t rowv = (size_t)(base + (vt_t >> 3) * 64 + (vt_t & 7)) * 1152;

#pragma unroll 1
  for (int h = 0; h < 12; ++h) {
    const int hoff = h * 32;
    // stage V transposed: vt[d][t]
    f16x8 vv = *(const f16x8*)&qkv[rowv + 768 + hoff + vt_d8];
#pragma unroll
    for (int j = 0; j < 8; ++j) vt[(vt_d8 + j) * 72 + vt_t] = vv[j];
    __syncthreads();

    // QK^T: q A-frag and k B-frags straight from global (16B/lane)
    f16x8 aq = *(const f16x8*)&qkv[rowq + hoff + quad * 8];
    f32x4 sim[4];
#pragma unroll
    for (int tj = 0; tj < 4; ++tj) {
      f16x8 bk = *(const f16x8*)&qkv[rowk[tj] + 384 + hoff + quad * 8];
      f32x4 z = {};
      sim[tj] = MFMA_F16(aq, bk, z);
    }
#pragma unroll
    for (int tj = 0; tj < 4; ++tj)
#pragma unroll
      for (int v = 0; v < 4; ++v) sim[tj][v] *= SCALE;

    // exact softmax; row r=quad*4+v lives in the quad's 16 lanes x 4 tj
    float pv[4][4];
#pragma unroll
    for (int v = 0; v < 4; ++v) {
      float m = fmaxf(fmaxf(sim[0][v], sim[1][v]), fmaxf(sim[2][v], sim[3][v]));
#pragma unroll
      for (int off = 1; off < 16; off <<= 1) m = fmaxf(m, __shfl_xor(m, off));
      float ssum = 0.f;
#pragma unroll
      for (int tj = 0; tj < 4; ++tj) {
        pv[tj][v] = __expf(sim[tj][v] - m);
        ssum += pv[tj][v];
      }
#pragma unroll
      for (int off = 1; off < 16; off <<= 1) ssum += __shfl_xor(ssum, off);
      float inv = 1.0f / ssum;
#pragma unroll
      for (int tj = 0; tj < 4; ++tj) pv[tj][v] *= inv;
    }
    // P -> LDS (C-layout -> A-frag layout round trip)
#pragma unroll
    for (int tj = 0; tj < 4; ++tj)
#pragma unroll
      for (int v = 0; v < 4; ++v)
        Pw[wave][(quad * 4 + v) * 72 + tj * 16 + lane15] = (f16)pv[tj][v];
    __syncthreads();  // conservative: P write -> read ordering

    // PV: [16x64] @ [64x32]
    f32x4 o[2] = {};
#pragma unroll
    for (int kk = 0; kk < 64; kk += 32) {
      f16x8 pa = *(const f16x8*)&Pw[wave][lane15 * 72 + kk + quad * 8];
#pragma unroll
      for (int tj = 0; tj < 2; ++tj) {
        f16x8 bvv = *(const f16x8*)&vt[(tj * 16 + lane15) * 72 + kk + quad * 8];
        o[tj] = MFMA_F16(pa, bvv, o[tj]);
      }
    }
#pragma unroll
    for (int tj = 0; tj < 2; ++tj)
#pragma unroll
      for (int v = 0; v < 4; ++v)
        ao[(wave * 16 + quad * 4 + v) * 392 + hoff + tj * 16 + lane15] = (f16)o[tj][v];
    __syncthreads();
  }

  // fused out-projection: [64,384] @ w_out + bias; wave covers 96 output cols
  const int n0 = wave * 96;
  float biasv[6];
#pragma unroll
  for (int tj = 0; tj < 6; ++tj) biasv[tj] = b_out[n0 + tj * 16 + lane15];
  f32x4 acc[4][6] = {};
  for (int ksi = 0; ksi < 12; ++ksi) {
    const int ks = ksi * 32;
    f16x8 af[4];
#pragma unroll
    for (int ti = 0; ti < 4; ++ti)
      af[ti] = *(const f16x8*)&ao[(ti * 16 + lane15) * 392 + ks + quad * 8];
#pragma unroll
    for (int tj = 0; tj < 6; ++tj) {
      f16x8 bf = *(const f16x8*)&woutT[(size_t)(n0 + tj * 16 + lane15) * 384 + ks + quad * 8];
#pragma unroll
      for (int ti = 0; ti < 4; ++ti) acc[ti][tj] = MFMA_F16(af[ti], bf, acc[ti][tj]);
    }
  }
#pragma unroll
  for (int ti = 0; ti < 4; ++ti)
#pragma unroll
    for (int v = 0; v < 4; ++v) {
      int t = ti * 16 + quad * 4 + v;
      size_t row = (size_t)(base + (t >> 3) * 64 + (t & 7)) * 384;
#pragma unroll
      for (int tj = 0; tj < 6; ++tj)
        out[row + n0 + tj * 16 + lane15] = acc[ti][tj][v] + biasv[tj];
    }
}

extern "C" void kernel_launch(void* const* d_in, const int* in_sizes, int n_in,
                              void* d_out, int out_size, void* d_ws, size_t ws_size,
                              hipStream_t stream) {
  const float* x = (const float*)d_in[0];
  const float* w_qkv = (const float*)d_in[1];
  const float* w_out = (const float*)d_in[2];
  const float* b_out = (const float*)d_in[3];
  float* out = (float*)d_out;

  if (ws_size < WS_NEEDED) return;  // deterministic guard: poison-level absmax => ws too small

  char* ws = (char*)d_ws;
  f16* wqkvT = (f16*)(ws + WQKVT_OFF);
  f16* woutT = (f16*)(ws + WOUTT_OFF);
  f16* qkv = (f16*)(ws + QKV_OFF);

  hipLaunchKernelGGL(k_prep, dim3(2304), dim3(256), 0, stream, w_qkv, w_out, wqkvT, woutT);
  hipLaunchKernelGGL(k_qkv, dim3(9216), dim3(256), 0, stream, x, wqkvT, qkv);
  hipLaunchKernelGGL(k_attn, dim3(2048), dim3(256), 0, stream, qkv, woutT, b_out, out);
}

// Round 2
// 768.551 us; speedup vs baseline: 1.0752x; 1.0752x over previous
//
#include <hip/hip_runtime.h>

typedef _Float16 f16;
typedef _Float16 f16x4 __attribute__((ext_vector_type(4)));
typedef _Float16 f16x8 __attribute__((ext_vector_type(8)));
typedef float f32x4 __attribute__((ext_vector_type(4)));

#define MFMA_F16(A, B, C) __builtin_amdgcn_mfma_f32_16x16x32_f16(A, B, C, 0, 0, 0)
// async global->LDS DMA, 16B per lane; LDS dest = wave-uniform base + lane*16
#define GLDS16(gp, lp)                                                        \
  __builtin_amdgcn_global_load_lds(                                           \
      (const __attribute__((address_space(1))) void*)(gp),                    \
      (__attribute__((address_space(3))) void*)(lp), 16, 0, 0)

// x: [32,64,64,384] fp32 -> windows of 8x8 -> 2048 windows x 64 tokens
// heads=12, dim_head=32, INNER=384, qkv cols = 1152
static constexpr int ROWS = 32 * 64 * 64;  // 131072 token rows
static constexpr float SCALE = 0.17677669529663687f;  // 32^-0.5

// workspace layout (bytes)
static constexpr size_t WQKVT_OFF = 0;                              // f16 [1152][384] (B^T)
static constexpr size_t WOUTT_OFF = (size_t)1152 * 384 * 2;         // f16 [384][384]  (B^T)
static constexpr size_t QKV_OFF   = WOUTT_OFF + (size_t)384 * 384 * 2;  // f16 [131072][1152]
static constexpr size_t WS_NEEDED = QKV_OFF + (size_t)ROWS * 1152 * 2;  // ~303 MB

// ---------------- weight prep: transpose + fp32->fp16 ----------------
__global__ __launch_bounds__(256) void k_prep(const float* __restrict__ wqkv,
                                              const float* __restrict__ wout,
                                              f16* __restrict__ wqkvT,
                                              f16* __restrict__ woutT) {
  int idx = blockIdx.x * 256 + threadIdx.x;
  if (idx < 1152 * 384) {
    int c = idx / 384, k = idx - c * 384;
    wqkvT[idx] = (f16)wqkv[k * 1152 + c];
  } else {
    int i = idx - 1152 * 384;
    if (i < 384 * 384) {
      int c = i / 384, k = i - c * 384;
      woutT[i] = (f16)wout[k * 384 + c];
    }
  }
}

// ---------------- QKV GEMM: [131072,384](fp32) @ [384,1152] -> fp16 ----------------
// 128x128 tile, BK=64, 4 waves in 2x2, 16x16x32 fp16 MFMA.
// v3: B double-buffered via async global_load_lds (zero staging VGPRs; linear LDS
//     layout with XOR-pre-swizzled GLOBAL source -> conflict-free ds_read_b128).
//     A prefetched in registers one step ahead; LDS (69.6KB) caps occupancy at
//     2 blocks/CU so the backend's register budget (256/wave) keeps the prefetch
//     live instead of sinking it (the v2 failure). One barrier per K-step.
__global__ __launch_bounds__(256) void k_qkv(const float* __restrict__ X,
                                             const f16* __restrict__ Wt,
                                             f16* __restrict__ qkv) {
  __shared__ f16 As[2][128 * 72];  // padded (72h=144B rows): frag reads conflict-free
  __shared__ f16 Bs[2][128 * 64];  // linear 128B rows, XOR-swizzled CONTENT

  const int tid = threadIdx.x;
  // XCD swizzle: id%8 = XCD (dispatch round-robin). Per XCD, 9 consecutive
  // blocks share one m-tile so the A-tile is fetched into that XCD's L2 once.
  const int id = blockIdx.x;          // 0..9215
  const int s = id & 7, t = id >> 3;  // t in [0,1152)
  const int n0 = (t % 9) * 128;
  const int m0 = (s * 128 + t / 9) * 128;

  const int lane = tid & 63, wave = tid >> 6;
  const int lane15 = lane & 15, quad = lane >> 4;
  const int wm = (wave >> 1) * 64, wn = (wave & 1) * 64;

  const int arow = tid >> 4;       // A staging: + l*16 -> row
  const int ac4 = (tid & 15) * 4;  // A staging: col group (4 floats)

  // B staging geometry: 16 chunks of 1KB (8 rows each); wave w stages chunks w*4..w*4+3.
  // LDS[nr][cb] holds global granule (cb ^ (nr&7)); within a chunk nr&7 == lane>>3.
  const int l8 = lane >> 3, cb = lane & 7;
  const int bswz = ((cb ^ l8) << 3);  // swizzled source col offset (halves)
  const f16* bsrc[4];
#pragma unroll
  for (int l = 0; l < 4; ++l)
    bsrc[l] = Wt + (size_t)(n0 + wave * 32 + l * 8 + l8) * 384 + bswz;

  float4 xv[8];
  f32x4 acc[4][4] = {};

  // ---- prologue: stage step 0 ----
#pragma unroll
  for (int l = 0; l < 8; ++l)
    xv[l] = *(const float4*)&X[(size_t)(m0 + l * 16 + arow) * 384 + ac4];
#pragma unroll
  for (int l = 0; l < 4; ++l)
    GLDS16(bsrc[l], &Bs[0][(wave * 4 + l) * 512]);
#pragma unroll
  for (int l = 0; l < 8; ++l) {
    f16x4 hv;
    hv[0] = (f16)xv[l].x; hv[1] = (f16)xv[l].y; hv[2] = (f16)xv[l].z; hv[3] = (f16)xv[l].w;
    *(f16x4*)&As[0][(l * 16 + arow) * 72 + ac4] = hv;
  }
  __syncthreads();

#pragma unroll
  for (int ksi = 0; ksi < 6; ++ksi) {
    const int cur = ksi & 1, nxt = cur ^ 1;
    const int ks = ksi * 64;

    if (ksi < 5) {
      // issue next-step loads EARLY: A -> regs, B -> async DMA into other buffer
#pragma unroll
      for (int l = 0; l < 8; ++l)
        xv[l] = *(const float4*)&X[(size_t)(m0 + l * 16 + arow) * 384 + ks + 64 + ac4];
#pragma unroll
      for (int l = 0; l < 4; ++l)
        GLDS16(bsrc[l] + ks + 64, &Bs[nxt][(wave * 4 + l) * 512]);
      __builtin_amdgcn_sched_barrier(0);  // pin load-issue above the MFMA phase
    }

    // ---- compute on buffer cur ----
#pragma unroll
    for (int kk = 0; kk < 2; ++kk) {
      f16x8 af[4], bf[4];
#pragma unroll
      for (int i = 0; i < 4; ++i)
        af[i] = *(const f16x8*)&As[cur][(wm + i * 16 + lane15) * 72 + kk * 32 + quad * 8];
#pragma unroll
      for (int j = 0; j < 4; ++j) {
        int nr = wn + j * 16 + lane15;
        int go = ((kk * 4 + quad) ^ (nr & 7)) << 3;  // un-swizzle on read
        bf[j] = *(const f16x8*)&Bs[cur][nr * 64 + go];
      }
#pragma unroll
      for (int i = 0; i < 4; ++i)
#pragma unroll
        for (int j = 0; j < 4; ++j)
          acc[i][j] = MFMA_F16(af[i], bf[j], acc[i][j]);
    }

    if (ksi < 5) {
      // write-late: convert prefetched A into the other buffer (waits vmcnt here,
      // ~a full MFMA phase after issue)
#pragma unroll
      for (int l = 0; l < 8; ++l) {
        f16x4 hv;
        hv[0] = (f16)xv[l].x; hv[1] = (f16)xv[l].y; hv[2] = (f16)xv[l].z; hv[3] = (f16)xv[l].w;
        *(f16x4*)&As[nxt][(l * 16 + arow) * 72 + ac4] = hv;
      }
    }
    __syncthreads();  // one barrier per K-step (drains B DMA for nxt too)
  }

  // epilogue: fp32 acc -> fp16, bounce through LDS for coalesced 16B stores
  f16* Cs = (f16*)As;  // needs 128*136*2 = 34,816 B <= 36,864 B
#pragma unroll
  for (int i = 0; i < 4; ++i)
#pragma unroll
    for (int j = 0; j < 4; ++j)
#pragma unroll
      for (int v = 0; v < 4; ++v)
        Cs[(wm + i * 16 + quad * 4 + v) * 136 + wn + j * 16 + lane15] = (f16)acc[i][j][v];
  __syncthreads();
#pragma unroll
  for (int l = 0; l < 8; ++l) {
    int idx = l * 256 + tid;
    int row = idx >> 4, c8 = (idx & 15) * 8;
    *(f16x8*)&qkv[(size_t)(m0 + row) * 1152 + n0 + c8] = *(const f16x8*)&Cs[row * 136 + c8];
  }
}

// ---------------- attention per window + fused out-projection ----------------
// block = 256 thr (4 waves), one block per window. wave w owns score rows w*16..w*16+15.
__global__ __launch_bounds__(256) void k_attn(const f16* __restrict__ qkv,
                                              const f16* __restrict__ woutT,
                                              const float* __restrict__ b_out,
                                              float* __restrict__ out) {
  __shared__ f16 vt[32 * 72];     // v^T for current head: [dim][64 tok + 8 pad]
  __shared__ f16 Pw[4][16 * 72];  // per-wave P tile [16][64+8]
  __shared__ f16 ao[64 * 392];    // attention output [64][384+8]
  // total LDS = 64,000 B -> 2 blocks/CU

  const int tid = threadIdx.x;
  const int lane = tid & 63, wave = tid >> 6;
  const int lane15 = lane & 15, quad = lane >> 4;

  const int blk = blockIdx.x;  // 0..2047
  const int b = blk >> 6, rem = blk & 63, wh = rem >> 3, ww = rem & 7;
  const int base = b * 4096 + wh * 512 + ww * 8;  // natural row of token (0,0)

  // per-lane source rows (token t -> natural row base + (t>>3)*64 + (t&7))
  const int tq = wave * 16 + lane15;
  const size_t rowq = (size_t)(base + (tq >> 3) * 64 + (tq & 7)) * 1152;
  size_t rowk[4];
#pragma unroll
  for (int tj = 0; tj < 4; ++tj) {
    int tk = tj * 16 + lane15;
    rowk[tj] = (size_t)(base + (tk >> 3) * 64 + (tk & 7)) * 1152;
  }
  const int vt_t = tid >> 2, vt_d8 = (tid & 3) * 8;
  const size_t rowv = (size_t)(base + (vt_t >> 3) * 64 + (vt_t & 7)) * 1152;

#pragma unroll 1
  for (int h = 0; h < 12; ++h) {
    const int hoff = h * 32;
    // stage V transposed: vt[d][t]
    f16x8 vv = *(const f16x8*)&qkv[rowv + 768 + hoff + vt_d8];
#pragma unroll
    for (int j = 0; j < 8; ++j) vt[(vt_d8 + j) * 72 + vt_t] = vv[j];
    __syncthreads();

    // QK^T: q A-frag and k B-frags straight from global (16B/lane)
    f16x8 aq = *(const f16x8*)&qkv[rowq + hoff + quad * 8];
    f32x4 sim[4];
#pragma unroll
    for (int tj = 0; tj < 4; ++tj) {
      f16x8 bk = *(const f16x8*)&qkv[rowk[tj] + 384 + hoff + quad * 8];
      f32x4 z = {};
      sim[tj] = MFMA_F16(aq, bk, z);
    }
#pragma unroll
    for (int tj = 0; tj < 4; ++tj)
#pragma unroll
      for (int v = 0; v < 4; ++v) sim[tj][v] *= SCALE;

    // exact softmax; row r=quad*4+v lives in the quad's 16 lanes x 4 tj
    float pv[4][4];
#pragma unroll
    for (int v = 0; v < 4; ++v) {
      float m = fmaxf(fmaxf(sim[0][v], sim[1][v]), fmaxf(sim[2][v], sim[3][v]));
#pragma unroll
      for (int off = 1; off < 16; off <<= 1) m = fmaxf(m, __shfl_xor(m, off));
      float ssum = 0.f;
#pragma unroll
      for (int tj = 0; tj < 4; ++tj) {
        pv[tj][v] = __expf(sim[tj][v] - m);
        ssum += pv[tj][v];
      }
#pragma unroll
      for (int off = 1; off < 16; off <<= 1) ssum += __shfl_xor(ssum, off);
      float inv = 1.0f / ssum;
#pragma unroll
      for (int tj = 0; tj < 4; ++tj) pv[tj][v] *= inv;
    }
    // P -> LDS (C-layout -> A-frag layout round trip)
#pragma unroll
    for (int tj = 0; tj < 4; ++tj)
#pragma unroll
      for (int v = 0; v < 4; ++v)
        Pw[wave][(quad * 4 + v) * 72 + tj * 16 + lane15] = (f16)pv[tj][v];
    __syncthreads();  // conservative: P write -> read ordering

    // PV: [16x64] @ [64x32]
    f32x4 o[2] = {};
#pragma unroll
    for (int kk = 0; kk < 64; kk += 32) {
      f16x8 pa = *(const f16x8*)&Pw[wave][lane15 * 72 + kk + quad * 8];
#pragma unroll
      for (int tj = 0; tj < 2; ++tj) {
        f16x8 bvv = *(const f16x8*)&vt[(tj * 16 + lane15) * 72 + kk + quad * 8];
        o[tj] = MFMA_F16(pa, bvv, o[tj]);
      }
    }
#pragma unroll
    for (int tj = 0; tj < 2; ++tj)
#pragma unroll
      for (int v = 0; v < 4; ++v)
        ao[(wave * 16 + quad * 4 + v) * 392 + hoff + tj * 16 + lane15] = (f16)o[tj][v];
    __syncthreads();
  }

  // fused out-projection: [64,384] @ w_out + bias; wave covers 96 output cols
  const int n0 = wave * 96;
  float biasv[6];
#pragma unroll
  for (int tj = 0; tj < 6; ++tj) biasv[tj] = b_out[n0 + tj * 16 + lane15];
  f32x4 acc[4][6] = {};
  for (int ksi = 0; ksi < 12; ++ksi) {
    const int ks = ksi * 32;
    f16x8 af[4];
#pragma unroll
    for (int ti = 0; ti < 4; ++ti)
      af[ti] = *(const f16x8*)&ao[(ti * 16 + lane15) * 392 + ks + quad * 8];
#pragma unroll
    for (int tj = 0; tj < 6; ++tj) {
      f16x8 bf = *(const f16x8*)&woutT[(size_t)(n0 + tj * 16 + lane15) * 384 + ks + quad * 8];
#pragma unroll
      for (int ti = 0; ti < 4; ++ti) acc[ti][tj] = MFMA_F16(af[ti], bf, acc[ti][tj]);
    }
  }
#pragma unroll
  for (int ti = 0; ti < 4; ++ti)
#pragma unroll
    for (int v = 0; v < 4; ++v) {
      int t = ti * 16 + quad * 4 + v;
      size_t row = (size_t)(base + (t >> 3) * 64 + (t & 7)) * 384;
#pragma unroll
      for (int tj = 0; tj < 6; ++tj)
        out[row + n0 + tj * 16 + lane15] = acc[ti][tj][v] + biasv[tj];
    }
}

extern "C" void kernel_launch(void* const* d_in, const int* in_sizes, int n_in,
                              void* d_out, int out_size, void* d_ws, size_t ws_size,
                              hipStream_t stream) {
  const float* x = (const float*)d_in[0];
  const float* w_qkv = (const float*)d_in[1];
  const float* w_out = (const float*)d_in[2];
  const float* b_out = (const float*)d_in[3];
  float* out = (float*)d_out;

  if (ws_size < WS_NEEDED) return;  // deterministic guard: poison-level absmax => ws too small

  char* ws = (char*)d_ws;
  f16* wqkvT = (f16*)(ws + WQKVT_OFF);
  f16* woutT = (f16*)(ws + WOUTT_OFF);
  f16* qkv = (f16*)(ws + QKV_OFF);

  hipLaunchKernelGGL(k_prep, dim3(2304), dim3(256), 0, stream, w_qkv, w_out, wqkvT, woutT);
  hipLaunchKernelGGL(k_qkv, dim3(9216), dim3(256), 0, stream, x, wqkvT, qkv);
  hipLaunchKernelGGL(k_attn, dim3(2048), dim3(256), 0, stream, qkv, woutT, b_out, out);
}

// Round 5
// 753.786 us; speedup vs baseline: 1.0963x; 1.0196x over previous
//
#include <hip/hip_runtime.h>

typedef _Float16 f16;
typedef _Float16 f16x4 __attribute__((ext_vector_type(4)));
typedef _Float16 f16x8 __attribute__((ext_vector_type(8)));
typedef float f32x4 __attribute__((ext_vector_type(4)));

#define MFMA_F16(A, B, C) __builtin_amdgcn_mfma_f32_16x16x32_f16(A, B, C, 0, 0, 0)
// async global->LDS DMA, 16B per lane; LDS dest = wave-uniform base + lane*16
#define GLDS16(gp, lp)                                                        \
  __builtin_amdgcn_global_load_lds(                                           \
      (const __attribute__((address_space(1))) void*)(gp),                    \
      (__attribute__((address_space(3))) void*)(lp), 16, 0, 0)

// x: [32,64,64,384] fp32 -> windows of 8x8 -> 2048 windows x 64 tokens
// heads=12, dim_head=32, INNER=384, qkv cols = 1152
static constexpr int ROWS = 32 * 64 * 64;  // 131072 token rows
static constexpr float SCALE = 0.17677669529663687f;  // 32^-0.5

// workspace layout (bytes). Xh (f16 copy of X) lives in d_out scratch space:
// 96MB < 192MB out buffer; k_attn overwrites out only at the very end.
static constexpr size_t WQKVT_OFF = 0;                              // f16 [1152][384] (B^T)
static constexpr size_t WOUTT_OFF = (size_t)1152 * 384 * 2;         // f16 [384][384]  (B^T)
static constexpr size_t QKV_OFF   = WOUTT_OFF + (size_t)384 * 384 * 2;  // f16 [131072][1152]
static constexpr size_t WS_NEEDED = QKV_OFF + (size_t)ROWS * 1152 * 2;  // ~303 MB

// ---------------- weight prep: transpose + fp32->fp16 ----------------
__global__ __launch_bounds__(256) void k_prep(const float* __restrict__ wqkv,
                                              const float* __restrict__ wout,
                                              f16* __restrict__ wqkvT,
                                              f16* __restrict__ woutT) {
  int idx = blockIdx.x * 256 + threadIdx.x;
  if (idx < 1152 * 384) {
    int c = idx / 384, k = idx - c * 384;
    wqkvT[idx] = (f16)wqkv[k * 1152 + c];
  } else {
    int i = idx - 1152 * 384;
    if (i < 384 * 384) {
      int c = i / 384, k = i - c * 384;
      woutT[i] = (f16)wout[k * 384 + c];
    }
  }
}

// ---------------- X fp32 -> f16 (so the GEMM can DMA-stage A) ----------------
__global__ __launch_bounds__(256) void k_cvt(const float* __restrict__ X,
                                             f16* __restrict__ Xh) {
  int idx = blockIdx.x * 256 + threadIdx.x;  // 4096 blocks -> 1,048,576 threads
#pragma unroll
  for (int i = 0; i < 12; ++i) {
    size_t j = (size_t)(idx + i * 1048576) * 4;  // 12,582,912 float4 total, exact cover
    float4 v = *(const float4*)&X[j];
    f16x4 h;
    h[0] = (f16)v.x; h[1] = (f16)v.y; h[2] = (f16)v.z; h[3] = (f16)v.w;
    *(f16x4*)&Xh[j] = h;
  }
}

// ---------------- QKV GEMM: [131072,384](f16) @ [384,1152] -> f16 ----------------
// v5: BM=BN=128, BK=64, 4 waves 2x2, BOTH operands staged via global_load_lds
//     (no staging VGPRs -> nothing for the compiler to sink; the v2/v3 failure).
//     Safe 2-phase pipeline (T3 minimum recipe): STAGE(next) at top of iter,
//     compute(cur), then __syncthreads() -- its vmcnt(0)+lgkmcnt(0)+barrier has
//     full compiler-fence semantics, so no issue-order/counted-vmcnt assumptions
//     (v4's race: scheduler interleaved independent DMAs, breaking "oldest 8").
//     DMA latency hides under the compute phase. LDS tiles linear [128][64]h
//     with XOR granule swizzle: source pre-swizzled, read XOR'd (rule #21).
__global__ __launch_bounds__(256, 2) void k_qkv(const f16* __restrict__ Xh,
                                                const f16* __restrict__ Wt,
                                                f16* __restrict__ qkv) {
  __shared__ __align__(16) f16 smem[4][128 * 64];  // As0,As1,Bs0,Bs1 = 64KB -> 2 blk/CU

  const int tid = threadIdx.x;
  // XCD swizzle: id%8 = XCD. Per XCD, 9 consecutive blocks share one m-tile.
  const int id = blockIdx.x;          // 0..9215
  const int s = id & 7, t = id >> 3;  // t in [0,1152)
  const int n0 = (t % 9) * 128;
  const int m0 = (s * 128 + t / 9) * 128;

  const int lane = tid & 63, wave = tid >> 6;
  const int lane15 = lane & 15, quad = lane >> 4;
  const int wm = (wave >> 1) * 64, wn = (wave & 1) * 64;

  // staging: chunk c = wave*4+l covers rows c*8..c*8+7 (1KB per wave-instr).
  // lane L: row-in-chunk r8 = L>>3, LDS granule slot g7 = L&7 (linear dest).
  // LDS slot g of row r must hold global granule g^(r&7)  (r&7 == r8 here).
  const int r8 = lane >> 3, g7 = lane & 7;
  const int sg = ((g7 ^ r8) << 3);  // pre-swizzled source granule offset (halves)
  const f16* asrc[4];
  const f16* bsrc[4];
#pragma unroll
  for (int l = 0; l < 4; ++l) {
    asrc[l] = Xh + (size_t)(m0 + (wave * 4 + l) * 8 + r8) * 384 + sg;
    bsrc[l] = Wt + (size_t)(n0 + (wave * 4 + l) * 8 + r8) * 384 + sg;
  }

#define STAGE(buf, ks)                                                      \
  do {                                                                      \
    _Pragma("unroll") for (int l = 0; l < 4; ++l)                           \
        GLDS16(asrc[l] + (ks), &smem[(buf)][(wave * 4 + l) * 512]);         \
    _Pragma("unroll") for (int l = 0; l < 4; ++l)                           \
        GLDS16(bsrc[l] + (ks), &smem[2 + (buf)][(wave * 4 + l) * 512]);     \
  } while (0)

  // read offset: row*64 halves + swizzled granule ((kk*4+quad)^(row&7))*8
#define LDSOFF(row, kk) ((row) * 64 + ((((kk) * 4 + quad) ^ ((row) & 7)) << 3))

  f32x4 acc[4][4] = {};

  // ---- prologue: stage tile 0, full drain (correct by construction) ----
  STAGE(0, 0);
  __syncthreads();

#pragma unroll
  for (int ti = 0; ti < 6; ++ti) {
    const int cur = ti & 1;
    // issue next tile's DMAs first; they land during the compute phase below.
    // Safe: buf cur^1 was last read in iter ti-1, whose closing __syncthreads
    // guarantees all waves finished reading it.
    if (ti < 5) STAGE(cur ^ 1, (ti + 1) * 64);
    __builtin_amdgcn_sched_barrier(0);  // pin DMA issue above the compute phase

#pragma unroll
    for (int kk = 0; kk < 2; ++kk) {
      f16x8 af[4], bf[4];
#pragma unroll
      for (int i = 0; i < 4; ++i)
        af[i] = *(const f16x8*)&smem[cur][LDSOFF(wm + i * 16 + lane15, kk)];
#pragma unroll
      for (int j = 0; j < 4; ++j)
        bf[j] = *(const f16x8*)&smem[2 + cur][LDSOFF(wn + j * 16 + lane15, kk)];
#pragma unroll
      for (int i = 0; i < 4; ++i)
#pragma unroll
        for (int j = 0; j < 4; ++j)
          acc[i][j] = MFMA_F16(af[i], bf[j], acc[i][j]);
    }

    // vmcnt(0)+lgkmcnt(0)+barrier with compiler-fence semantics: next tile's
    // DMAs (issued above, hidden under compute) are complete; all waves done
    // reading cur before anyone restages it next iteration.
    __syncthreads();
  }
#undef STAGE
#undef LDSOFF

  // epilogue: fp32 acc -> fp16, bounce through LDS for coalesced 16B stores
  f16* Cs = (f16*)smem;  // needs 128*136*2 = 34,816 B <= 65,536 B
#pragma unroll
  for (int i = 0; i < 4; ++i)
#pragma unroll
    for (int j = 0; j < 4; ++j)
#pragma unroll
      for (int v = 0; v < 4; ++v)
        Cs[(wm + i * 16 + quad * 4 + v) * 136 + wn + j * 16 + lane15] = (f16)acc[i][j][v];
  __syncthreads();
#pragma unroll
  for (int l = 0; l < 8; ++l) {
    int idx = l * 256 + tid;
    int row = idx >> 4, c8 = (idx & 15) * 8;
    *(f16x8*)&qkv[(size_t)(m0 + row) * 1152 + n0 + c8] = *(const f16x8*)&Cs[row * 136 + c8];
  }
}

// ---------------- attention per window + fused out-projection ----------------
// block = 256 thr (4 waves), one block per window. wave w owns score rows w*16..w*16+15.
__global__ __launch_bounds__(256) void k_attn(const f16* __restrict__ qkv,
                                              const f16* __restrict__ woutT,
                                              const float* __restrict__ b_out,
                                              float* __restrict__ out) {
  __shared__ f16 vt[32 * 72];     // v^T for current head: [dim][64 tok + 8 pad]
  __shared__ f16 Pw[4][16 * 72];  // per-wave P tile [16][64+8]
  __shared__ f16 ao[64 * 392];    // attention output [64][384+8]
  // total LDS = 64,000 B -> 2 blocks/CU

  const int tid = threadIdx.x;
  const int lane = tid & 63, wave = tid >> 6;
  const int lane15 = lane & 15, quad = lane >> 4;

  const int blk = blockIdx.x;  // 0..2047
  const int b = blk >> 6, rem = blk & 63, wh = rem >> 3, ww = rem & 7;
  const int base = b * 4096 + wh * 512 + ww * 8;  // natural row of token (0,0)

  // per-lane source rows (token t -> natural row base + (t>>3)*64 + (t&7))
  const int tq = wave * 16 + lane15;
  const size_t rowq = (size_t)(base + (tq >> 3) * 64 + (tq & 7)) * 1152;
  size_t rowk[4];
#pragma unroll
  for (int tj = 0; tj < 4; ++tj) {
    int tk = tj * 16 + lane15;
    rowk[tj] = (size_t)(base + (tk >> 3) * 64 + (tk & 7)) * 1152;
  }
  const int vt_t = tid >> 2, vt_d8 = (tid & 3) * 8;
  const size_t rowv = (size_t)(base + (vt_t >> 3) * 64 + (vt_t & 7)) * 1152;

#pragma unroll 1
  for (int h = 0; h < 12; ++h) {
    const int hoff = h * 32;
    // stage V transposed: vt[d][t]
    f16x8 vv = *(const f16x8*)&qkv[rowv + 768 + hoff + vt_d8];
#pragma unroll
    for (int j = 0; j < 8; ++j) vt[(vt_d8 + j) * 72 + vt_t] = vv[j];
    __syncthreads();

    // QK^T: q A-frag and k B-frags straight from global (16B/lane)
    f16x8 aq = *(const f16x8*)&qkv[rowq + hoff + quad * 8];
    f32x4 sim[4];
#pragma unroll
    for (int tj = 0; tj < 4; ++tj) {
      f16x8 bk = *(const f16x8*)&qkv[rowk[tj] + 384 + hoff + quad * 8];
      f32x4 z = {};
      sim[tj] = MFMA_F16(aq, bk, z);
    }
#pragma unroll
    for (int tj = 0; tj < 4; ++tj)
#pragma unroll
      for (int v = 0; v < 4; ++v) sim[tj][v] *= SCALE;

    // exact softmax; row r=quad*4+v lives in the quad's 16 lanes x 4 tj
    float pv[4][4];
#pragma unroll
    for (int v = 0; v < 4; ++v) {
      float m = fmaxf(fmaxf(sim[0][v], sim[1][v]), fmaxf(sim[2][v], sim[3][v]));
#pragma unroll
      for (int off = 1; off < 16; off <<= 1) m = fmaxf(m, __shfl_xor(m, off));
      float ssum = 0.f;
#pragma unroll
      for (int tj = 0; tj < 4; ++tj) {
        pv[tj][v] = __expf(sim[tj][v] - m);
        ssum += pv[tj][v];
      }
#pragma unroll
      for (int off = 1; off < 16; off <<= 1) ssum += __shfl_xor(ssum, off);
      float inv = 1.0f / ssum;
#pragma unroll
      for (int tj = 0; tj < 4; ++tj) pv[tj][v] *= inv;
    }
    // P -> LDS (C-layout -> A-frag layout round trip)
#pragma unroll
    for (int tj = 0; tj < 4; ++tj)
#pragma unroll
      for (int v = 0; v < 4; ++v)
        Pw[wave][(quad * 4 + v) * 72 + tj * 16 + lane15] = (f16)pv[tj][v];
    __syncthreads();  // conservative: P write -> read ordering

    // PV: [16x64] @ [64x32]
    f32x4 o[2] = {};
#pragma unroll
    for (int kk = 0; kk < 64; kk += 32) {
      f16x8 pa = *(const f16x8*)&Pw[wave][lane15 * 72 + kk + quad * 8];
#pragma unroll
      for (int tj = 0; tj < 2; ++tj) {
        f16x8 bvv = *(const f16x8*)&vt[(tj * 16 + lane15) * 72 + kk + quad * 8];
        o[tj] = MFMA_F16(pa, bvv, o[tj]);
      }
    }
#pragma unroll
    for (int tj = 0; tj < 2; ++tj)
#pragma unroll
      for (int v = 0; v < 4; ++v)
        ao[(wave * 16 + quad * 4 + v) * 392 + hoff + tj * 16 + lane15] = (f16)o[tj][v];
    __syncthreads();
  }

  // fused out-projection: [64,384] @ w_out + bias; wave covers 96 output cols
  const int n0 = wave * 96;
  float biasv[6];
#pragma unroll
  for (int tj = 0; tj < 6; ++tj) biasv[tj] = b_out[n0 + tj * 16 + lane15];
  f32x4 acc[4][6] = {};
  for (int ksi = 0; ksi < 12; ++ksi) {
    const int ks = ksi * 32;
    f16x8 af[4];
#pragma unroll
    for (int ti = 0; ti < 4; ++ti)
      af[ti] = *(const f16x8*)&ao[(ti * 16 + lane15) * 392 + ks + quad * 8];
#pragma unroll
    for (int tj = 0; tj < 6; ++tj) {
      f16x8 bf = *(const f16x8*)&woutT[(size_t)(n0 + tj * 16 + lane15) * 384 + ks + quad * 8];
#pragma unroll
      for (int ti = 0; ti < 4; ++ti) acc[ti][tj] = MFMA_F16(af[ti], bf, acc[ti][tj]);
    }
  }
#pragma unroll
  for (int ti = 0; ti < 4; ++ti)
#pragma unroll
    for (int v = 0; v < 4; ++v) {
      int t = ti * 16 + quad * 4 + v;
      size_t row = (size_t)(base + (t >> 3) * 64 + (t & 7)) * 384;
#pragma unroll
      for (int tj = 0; tj < 6; ++tj)
        out[row + n0 + tj * 16 + lane15] = acc[ti][tj][v] + biasv[tj];
    }
}

extern "C" void kernel_launch(void* const* d_in, const int* in_sizes, int n_in,
                              void* d_out, int out_size, void* d_ws, size_t ws_size,
                              hipStream_t stream) {
  const float* x = (const float*)d_in[0];
  const float* w_qkv = (const float*)d_in[1];
  const float* w_out = (const float*)d_in[2];
  const float* b_out = (const float*)d_in[3];
  float* out = (float*)d_out;

  if (ws_size < WS_NEEDED) return;  // deterministic guard: poison-level absmax => ws too small

  char* ws = (char*)d_ws;
  f16* wqkvT = (f16*)(ws + WQKVT_OFF);
  f16* woutT = (f16*)(ws + WOUTT_OFF);
  f16* qkv = (f16*)(ws + QKV_OFF);
  f16* Xh = (f16*)d_out;  // scratch: 96MB f16 copy of X, fully dead before k_attn writes out

  hipLaunchKernelGGL(k_prep, dim3(2304), dim3(256), 0, stream, w_qkv, w_out, wqkvT, woutT);
  hipLaunchKernelGGL(k_cvt, dim3(4096), dim3(256), 0, stream, x, Xh);
  hipLaunchKernelGGL(k_qkv, dim3(9216), dim3(256), 0, stream, Xh, wqkvT, qkv);
  hipLaunchKernelGGL(k_attn, dim3(2048), dim3(256), 0, stream, qkv, woutT, b_out, out);
}

// Round 6
// 723.818 us; speedup vs baseline: 1.1417x; 1.0414x over previous
//
#include <hip/hip_runtime.h>

typedef _Float16 f16;
typedef _Float16 f16x4 __attribute__((ext_vector_type(4)));
typedef _Float16 f16x8 __attribute__((ext_vector_type(8)));
typedef float f32x4 __attribute__((ext_vector_type(4)));

#define MFMA_F16(A, B, C) __builtin_amdgcn_mfma_f32_16x16x32_f16(A, B, C, 0, 0, 0)
// async global->LDS DMA, 16B per lane; LDS dest = wave-uniform base + lane*16
#define GLDS16(gp, lp)                                                        \
  __builtin_amdgcn_global_load_lds(                                           \
      (const __attribute__((address_space(1))) void*)(gp),                    \
      (__attribute__((address_space(3))) void*)(lp), 16, 0, 0)

// x: [32,64,64,384] fp32 -> windows of 8x8 -> 2048 windows x 64 tokens
// heads=12, dim_head=32, INNER=384, qkv cols = 1152
static constexpr int ROWS = 32 * 64 * 64;  // 131072 token rows
static constexpr float SCALE = 0.17677669529663687f;  // 32^-0.5

// workspace layout (bytes). Xh (f16 copy of X) lives in d_out scratch space:
// 96MB < 192MB out buffer; out is written only by the final k_out kernel.
static constexpr size_t WQKVT_OFF = 0;                              // f16 [1152][384] (B^T)
static constexpr size_t WOUTT_OFF = (size_t)1152 * 384 * 2;         // f16 [384][384]  (B^T)
static constexpr size_t QKV_OFF   = WOUTT_OFF + (size_t)384 * 384 * 2;  // f16 [131072][1152]
static constexpr size_t WS_NEEDED = QKV_OFF + (size_t)ROWS * 1152 * 2;  // ~303 MB

// ---------------- weight prep: transpose + fp32->fp16 (+ fold SCALE into Wq) ----
__global__ __launch_bounds__(256) void k_prep(const float* __restrict__ wqkv,
                                              const float* __restrict__ wout,
                                              f16* __restrict__ wqkvT,
                                              f16* __restrict__ woutT) {
  int idx = blockIdx.x * 256 + threadIdx.x;
  if (idx < 1152 * 384) {
    int c = idx / 384, k = idx - c * 384;
    float w = wqkv[k * 1152 + c];
    wqkvT[idx] = (f16)(c < 384 ? w * SCALE : w);  // Q cols pre-scaled
  } else {
    int i = idx - 1152 * 384;
    if (i < 384 * 384) {
      int c = i / 384, k = i - c * 384;
      woutT[i] = (f16)wout[k * 384 + c];
    }
  }
}

// ---------------- X fp32 -> f16 (so the GEMM can DMA-stage A) ----------------
__global__ __launch_bounds__(256) void k_cvt(const float* __restrict__ X,
                                             f16* __restrict__ Xh) {
  int idx = blockIdx.x * 256 + threadIdx.x;  // 4096 blocks -> 1,048,576 threads
#pragma unroll
  for (int i = 0; i < 12; ++i) {
    size_t j = (size_t)(idx + i * 1048576) * 4;  // 12,582,912 float4 total, exact cover
    float4 v = *(const float4*)&X[j];
    f16x4 h;
    h[0] = (f16)v.x; h[1] = (f16)v.y; h[2] = (f16)v.z; h[3] = (f16)v.w;
    *(f16x4*)&Xh[j] = h;
  }
}

// ---------------- QKV GEMM: [131072,384](f16) @ [384,1152] -> f16 ----------------
// v5 structure (verified): DMA-staged both operands, safe 2-phase pipeline,
// XOR granule swizzle (source pre-swizzled, read XOR'd).
__global__ __launch_bounds__(256, 2) void k_qkv(const f16* __restrict__ Xh,
                                                const f16* __restrict__ Wt,
                                                f16* __restrict__ qkv) {
  __shared__ __align__(16) f16 smem[4][128 * 64];  // As0,As1,Bs0,Bs1 = 64KB -> 2 blk/CU

  const int tid = threadIdx.x;
  const int id = blockIdx.x;          // 0..9215
  const int s = id & 7, t = id >> 3;  // t in [0,1152)
  const int n0 = (t % 9) * 128;
  const int m0 = (s * 128 + t / 9) * 128;

  const int lane = tid & 63, wave = tid >> 6;
  const int lane15 = lane & 15, quad = lane >> 4;
  const int wm = (wave >> 1) * 64, wn = (wave & 1) * 64;

  const int r8 = lane >> 3, g7 = lane & 7;
  const int sg = ((g7 ^ r8) << 3);  // pre-swizzled source granule offset (halves)
  const f16* asrc[4];
  const f16* bsrc[4];
#pragma unroll
  for (int l = 0; l < 4; ++l) {
    asrc[l] = Xh + (size_t)(m0 + (wave * 4 + l) * 8 + r8) * 384 + sg;
    bsrc[l] = Wt + (size_t)(n0 + (wave * 4 + l) * 8 + r8) * 384 + sg;
  }

#define STAGE(buf, ks)                                                      \
  do {                                                                      \
    _Pragma("unroll") for (int l = 0; l < 4; ++l)                           \
        GLDS16(asrc[l] + (ks), &smem[(buf)][(wave * 4 + l) * 512]);         \
    _Pragma("unroll") for (int l = 0; l < 4; ++l)                           \
        GLDS16(bsrc[l] + (ks), &smem[2 + (buf)][(wave * 4 + l) * 512]);     \
  } while (0)

#define LDSOFF(row, kk) ((row) * 64 + ((((kk) * 4 + quad) ^ ((row) & 7)) << 3))

  f32x4 acc[4][4] = {};

  STAGE(0, 0);
  __syncthreads();

#pragma unroll
  for (int ti = 0; ti < 6; ++ti) {
    const int cur = ti & 1;
    if (ti < 5) STAGE(cur ^ 1, (ti + 1) * 64);
    __builtin_amdgcn_sched_barrier(0);  // pin DMA issue above the compute phase

#pragma unroll
    for (int kk = 0; kk < 2; ++kk) {
      f16x8 af[4], bf[4];
#pragma unroll
      for (int i = 0; i < 4; ++i)
        af[i] = *(const f16x8*)&smem[cur][LDSOFF(wm + i * 16 + lane15, kk)];
#pragma unroll
      for (int j = 0; j < 4; ++j)
        bf[j] = *(const f16x8*)&smem[2 + cur][LDSOFF(wn + j * 16 + lane15, kk)];
#pragma unroll
      for (int i = 0; i < 4; ++i)
#pragma unroll
        for (int j = 0; j < 4; ++j)
          acc[i][j] = MFMA_F16(af[i], bf[j], acc[i][j]);
    }
    __syncthreads();
  }
#undef STAGE
#undef LDSOFF

  // epilogue: fp32 acc -> fp16, bounce through LDS for coalesced 16B stores
  f16* Cs = (f16*)smem;
#pragma unroll
  for (int i = 0; i < 4; ++i)
#pragma unroll
    for (int j = 0; j < 4; ++j)
#pragma unroll
      for (int v = 0; v < 4; ++v)
        Cs[(wm + i * 16 + quad * 4 + v) * 136 + wn + j * 16 + lane15] = (f16)acc[i][j][v];
  __syncthreads();
#pragma unroll
  for (int l = 0; l < 8; ++l) {
    int idx = l * 256 + tid;
    int row = idx >> 4, c8 = (idx & 15) * 8;
    *(f16x8*)&qkv[(size_t)(m0 + row) * 1152 + n0 + c8] = *(const f16x8*)&Cs[row * 136 + c8];
  }
}

// ---------------- attention: wave-per-head, zero barriers ----------------
// block = 256 thr (4 waves), one block per window. Wave w owns heads {w, w+4, w+8},
// processing each ENTIRE head (64x64 scores) with wave-private LDS -> no
// __syncthreads at all; waves drift for latency hiding. PV output (pre-projection)
// is written into the dead Q columns of qkv (read-before-write within the wave,
// head-disjoint across waves -> race-free), consumed by k_out afterwards.
__global__ __launch_bounds__(256, 3) void k_attn(f16* __restrict__ qkv) {
  __shared__ f16 vt[4][32 * 72];  // per-wave V^T [d][tok+pad]    18,432 B
  __shared__ f16 Pt[4][16 * 72];  // per-wave P row-tile transpose  9,216 B

  const int tid = threadIdx.x;
  const int lane = tid & 63, wave = tid >> 6;
  const int lane15 = lane & 15, quad = lane >> 4;

  const int blk = blockIdx.x;  // 0..2047
  const int b = blk >> 6, rem = blk & 63, wh = rem >> 3, ww = rem & 7;
  const int base = b * 4096 + wh * 512 + ww * 8;  // natural row of token (0,0)

  // token t -> natural row: base + (t>>3)*64 + (t&7)
  size_t rowA[4];  // rows for Q tile i / K tile j (same formula)
#pragma unroll
  for (int i = 0; i < 4; ++i) {
    int t = i * 16 + lane15;
    rowA[i] = (size_t)(base + (t >> 3) * 64 + (t & 7)) * 1152;
  }
  const size_t rowV = (size_t)(base + (lane >> 3) * 64 + (lane & 7)) * 1152;

  f16* vtw = &vt[wave][0];
  f16* ptw = &Pt[wave][0];

#pragma unroll 1
  for (int hh = 0; hh < 3; ++hh) {
    const int h = wave + hh * 4;
    const int hoff = h * 32;

    // stage V^T (wave-private): vt[d][tok], tok = lane
#pragma unroll
    for (int g = 0; g < 4; ++g) {
      f16x8 vv = *(const f16x8*)&qkv[rowV + 768 + hoff + g * 8];
#pragma unroll
      for (int e = 0; e < 8; ++e) vtw[(g * 8 + e) * 72 + lane] = vv[e];
    }

    // QK^T: full 64x64 in one wave (4x4 tiles of 16x16x32). SCALE pre-folded.
    f16x8 af[4], bk[4];
#pragma unroll
    for (int i = 0; i < 4; ++i)
      af[i] = *(const f16x8*)&qkv[rowA[i] + hoff + quad * 8];
#pragma unroll
    for (int j = 0; j < 4; ++j)
      bk[j] = *(const f16x8*)&qkv[rowA[j] + 384 + hoff + quad * 8];
    f32x4 sim[4][4];
#pragma unroll
    for (int i = 0; i < 4; ++i)
#pragma unroll
      for (int j = 0; j < 4; ++j) {
        f32x4 z = {};
        sim[i][j] = MFMA_F16(af[i], bk[j], z);
      }

    // exact softmax, wave-local: row r=quad*4+v of tile i lives in the quad's
    // 16 lanes x 4 j-tiles
#pragma unroll
    for (int i = 0; i < 4; ++i)
#pragma unroll
      for (int v = 0; v < 4; ++v) {
        float m = fmaxf(fmaxf(sim[i][0][v], sim[i][1][v]),
                        fmaxf(sim[i][2][v], sim[i][3][v]));
#pragma unroll
        for (int off = 1; off < 16; off <<= 1) m = fmaxf(m, __shfl_xor(m, off));
        float ssum = 0.f;
#pragma unroll
        for (int j = 0; j < 4; ++j) {
          sim[i][j][v] = __expf(sim[i][j][v] - m);
          ssum += sim[i][j][v];
        }
#pragma unroll
        for (int off = 1; off < 16; off <<= 1) ssum += __shfl_xor(ssum, off);
        float inv = 1.0f / ssum;
#pragma unroll
        for (int j = 0; j < 4; ++j) sim[i][j][v] *= inv;
      }

    // V B-fragments (loaded once per head, reused for all 4 row-tiles)
    f16x8 bV[2][2];
#pragma unroll
    for (int j2 = 0; j2 < 2; ++j2)
#pragma unroll
      for (int kk = 0; kk < 2; ++kk)
        bV[j2][kk] = *(const f16x8*)&vtw[(j2 * 16 + lane15) * 72 + kk * 32 + quad * 8];

    // PV per row-tile i: P C-layout -> LDS -> A-frag (wave-private, compiler
    // inserts the lgkm waits), MFMA, write AO into the dead Q slot of qkv.
#pragma unroll
    for (int i = 0; i < 4; ++i) {
#pragma unroll
      for (int j = 0; j < 4; ++j)
#pragma unroll
        for (int v = 0; v < 4; ++v)
          ptw[(quad * 4 + v) * 72 + j * 16 + lane15] = (f16)sim[i][j][v];
      f32x4 o[2] = {};
#pragma unroll
      for (int kk = 0; kk < 2; ++kk) {
        f16x8 pa = *(const f16x8*)&ptw[lane15 * 72 + kk * 32 + quad * 8];
#pragma unroll
        for (int j2 = 0; j2 < 2; ++j2) o[j2] = MFMA_F16(pa, bV[j2][kk], o[j2]);
      }
#pragma unroll
      for (int j2 = 0; j2 < 2; ++j2)
#pragma unroll
        for (int v = 0; v < 4; ++v) {
          int t = i * 16 + quad * 4 + v;
          size_t row = (size_t)(base + (t >> 3) * 64 + (t & 7)) * 1152;
          qkv[row + hoff + j2 * 16 + lane15] = (f16)o[j2][v];
        }
    }
  }
}

// ---------------- out-projection GEMM: AO[131072,384] @ wout + bias -> fp32 ----
// Clone of k_qkv's verified DMA/2-phase structure. A = qkv Q-section (stride 1152).
__global__ __launch_bounds__(256, 2) void k_out(const f16* __restrict__ AO,
                                                const f16* __restrict__ Wt,
                                                const float* __restrict__ bias,
                                                float* __restrict__ out) {
  __shared__ __align__(16) f16 smem[4][128 * 64];

  const int tid = threadIdx.x;
  const int id = blockIdx.x;          // 0..3071
  const int s = id & 7, t = id >> 3;  // t in [0,384)
  const int n0 = (t % 3) * 128;
  const int m0 = (s * 128 + t / 3) * 128;  // 128 contiguous m-tiles per XCD

  const int lane = tid & 63, wave = tid >> 6;
  const int lane15 = lane & 15, quad = lane >> 4;
  const int wm = (wave >> 1) * 64, wn = (wave & 1) * 64;

  const int r8 = lane >> 3, g7 = lane & 7;
  const int sg = ((g7 ^ r8) << 3);
  const f16* asrc[4];
  const f16* bsrc[4];
#pragma unroll
  for (int l = 0; l < 4; ++l) {
    asrc[l] = AO + (size_t)(m0 + (wave * 4 + l) * 8 + r8) * 1152 + sg;  // stride 1152!
    bsrc[l] = Wt + (size_t)(n0 + (wave * 4 + l) * 8 + r8) * 384 + sg;
  }

#define STAGE(buf, ks)                                                      \
  do {                                                                      \
    _Pragma("unroll") for (int l = 0; l < 4; ++l)                           \
        GLDS16(asrc[l] + (ks), &smem[(buf)][(wave * 4 + l) * 512]);         \
    _Pragma("unroll") for (int l = 0; l < 4; ++l)                           \
        GLDS16(bsrc[l] + (ks), &smem[2 + (buf)][(wave * 4 + l) * 512]);     \
  } while (0)

#define LDSOFF(row, kk) ((row) * 64 + ((((kk) * 4 + quad) ^ ((row) & 7)) << 3))

  f32x4 acc[4][4] = {};

  STAGE(0, 0);
  __syncthreads();

#pragma unroll
  for (int ti = 0; ti < 6; ++ti) {
    const int cur = ti & 1;
    if (ti < 5) STAGE(cur ^ 1, (ti + 1) * 64);
    __builtin_amdgcn_sched_barrier(0);

#pragma unroll
    for (int kk = 0; kk < 2; ++kk) {
      f16x8 af[4], bf[4];
#pragma unroll
      for (int i = 0; i < 4; ++i)
        af[i] = *(const f16x8*)&smem[cur][LDSOFF(wm + i * 16 + lane15, kk)];
#pragma unroll
      for (int j = 0; j < 4; ++j)
        bf[j] = *(const f16x8*)&smem[2 + cur][LDSOFF(wn + j * 16 + lane15, kk)];
#pragma unroll
      for (int i = 0; i < 4; ++i)
#pragma unroll
        for (int j = 0; j < 4; ++j)
          acc[i][j] = MFMA_F16(af[i], bf[j], acc[i][j]);
    }
    __syncthreads();
  }
#undef STAGE
#undef LDSOFF

  // epilogue: bias add + direct fp32 stores (quad = 64B contiguous per instr)
  float bj[4];
#pragma unroll
  for (int j = 0; j < 4; ++j) bj[j] = bias[n0 + wn + j * 16 + lane15];
#pragma unroll
  for (int i = 0; i < 4; ++i)
#pragma unroll
    for (int j = 0; j < 4; ++j)
#pragma unroll
      for (int v = 0; v < 4; ++v)
        out[(size_t)(m0 + wm + i * 16 + quad * 4 + v) * 384 + n0 + wn + j * 16 + lane15] =
            acc[i][j][v] + bj[j];
}

extern "C" void kernel_launch(void* const* d_in, const int* in_sizes, int n_in,
                              void* d_out, int out_size, void* d_ws, size_t ws_size,
                              hipStream_t stream) {
  const float* x = (const float*)d_in[0];
  const float* w_qkv = (const float*)d_in[1];
  const float* w_out = (const float*)d_in[2];
  const float* b_out = (const float*)d_in[3];
  float* out = (float*)d_out;

  if (ws_size < WS_NEEDED) return;  // deterministic guard: poison-level absmax => ws too small

  char* ws = (char*)d_ws;
  f16* wqkvT = (f16*)(ws + WQKVT_OFF);
  f16* woutT = (f16*)(ws + WOUTT_OFF);
  f16* qkv = (f16*)(ws + QKV_OFF);
  f16* Xh = (f16*)d_out;  // scratch: 96MB f16 copy of X, fully dead before k_out writes out

  hipLaunchKernelGGL(k_prep, dim3(2304), dim3(256), 0, stream, w_qkv, w_out, wqkvT, woutT);
  hipLaunchKernelGGL(k_cvt, dim3(4096), dim3(256), 0, stream, x, Xh);
  hipLaunchKernelGGL(k_qkv, dim3(9216), dim3(256), 0, stream, Xh, wqkvT, qkv);
  hipLaunchKernelGGL(k_attn, dim3(2048), dim3(256), 0, stream, qkv);
  hipLaunchKernelGGL(k_out, dim3(3072), dim3(256), 0, stream, qkv, woutT, b_out, out);
}